// Round 1
// baseline (1406.397 us; speedup 1.0000x reference)
//
#include <hip/hip_runtime.h>
#include <hip/hip_bf16.h>

#define LEN_C 512
#define R_DIM 4
#define S_DIM 8
#define E_DIM 8
#define T_DIM 2048
#define Q_DIM (R_DIM * S_DIM)            // 32
#define W_ELEMS (Q_DIM * LEN_C)          // 16384
#define PER_T (Q_DIM * E_DIM * LEN_C)    // 131072 floats per t
#define LR_CONST 0.001f

// ---------------------------------------------------------------------------
// Kernel 1: error[e] = Dis[e, LEN_C-1] - sum_{q,n} Fx[q,e,n] * W0[q,n]
// One block, 256 threads.
// ---------------------------------------------------------------------------
__global__ __launch_bounds__(256) void grad_kernel(
    const float* __restrict__ Fx, const float* __restrict__ Dis,
    const float* __restrict__ W0, float* __restrict__ err) {
  __shared__ float lds[4 * 8];
  float p[E_DIM];
#pragma unroll
  for (int e = 0; e < E_DIM; ++e) p[e] = 0.0f;

  for (int idx = threadIdx.x; idx < W_ELEMS; idx += 256) {
    const int q = idx >> 9;          // / LEN_C
    const int n = idx & (LEN_C - 1);
    const float w = W0[idx];
    const float* f = Fx + ((size_t)q * E_DIM) * LEN_C + n;
#pragma unroll
    for (int e = 0; e < E_DIM; ++e) p[e] += f[e * LEN_C] * w;
  }

  const int lane = threadIdx.x & 63;
  const int wave = threadIdx.x >> 6;
#pragma unroll
  for (int e = 0; e < E_DIM; ++e) {
    float v = p[e];
    for (int off = 32; off; off >>= 1) v += __shfl_down(v, off, 64);
    if (lane == 0) lds[wave * 8 + e] = v;
  }
  __syncthreads();
  if (threadIdx.x < E_DIM) {
    const float anti = lds[threadIdx.x] + lds[8 + threadIdx.x] +
                       lds[16 + threadIdx.x] + lds[24 + threadIdx.x];
    err[threadIdx.x] = Dis[threadIdx.x * LEN_C + (LEN_C - 1)] - anti;
  }
}

// ---------------------------------------------------------------------------
// Kernel 2: cw[q,n] = W0[q,n] + LR * sum_e err[e] * Fx[q,e,n]
// 64 blocks x 256 threads (16384 elements).
// ---------------------------------------------------------------------------
__global__ __launch_bounds__(256) void cw_kernel(
    const float* __restrict__ Fx, const float* __restrict__ W0,
    const float* __restrict__ err, float* __restrict__ cw) {
  const int idx = blockIdx.x * 256 + threadIdx.x;
  const int q = idx >> 9;
  const int n = idx & (LEN_C - 1);
  const float* f = Fx + ((size_t)q * E_DIM) * LEN_C + n;
  float s = 0.0f;
#pragma unroll
  for (int e = 0; e < E_DIM; ++e) s += err[e] * f[e * LEN_C];
  cw[idx] = W0[idx] + LR_CONST * s;
}

// ---------------------------------------------------------------------------
// Kernel 3: anti_noise[t,e] = sum_{q,n} Fx_extend[t,q,e,n] * cw[q,n]
// One block per t (2048 blocks), 256 threads = 4 waves.
// Wave w owns q = w + 4*i (i=0..7). For each q the lane's cw float4 pair is
// loaded ONCE into registers and reused across all 8 e values.
// ---------------------------------------------------------------------------
__global__ __launch_bounds__(256) void adapt_kernel(
    const float* __restrict__ fxe, const float* __restrict__ cw,
    float* __restrict__ out) {
  const int t = blockIdx.x;
  const int lane = threadIdx.x & 63;
  const int wave = threadIdx.x >> 6;
  const float* base = fxe + (size_t)t * PER_T;

  float acc[E_DIM];
#pragma unroll
  for (int e = 0; e < E_DIM; ++e) acc[e] = 0.0f;

  // Hoist this lane's control-weight fragments into registers.
  float4 cwa[8], cwb[8];
#pragma unroll
  for (int i = 0; i < 8; ++i) {
    const int q = wave + 4 * i;
    const float4* c = (const float4*)(cw + q * LEN_C);
    cwa[i] = c[lane];
    cwb[i] = c[lane + 64];
  }

#pragma unroll
  for (int i = 0; i < 8; ++i) {
    const int q = wave + 4 * i;
    const float4* fb = (const float4*)(base + (size_t)q * (E_DIM * LEN_C));
#pragma unroll
    for (int e = 0; e < E_DIM; ++e) {
      const float4 fa = fb[e * 128 + lane];
      const float4 fc = fb[e * 128 + lane + 64];
      acc[e] += fa.x * cwa[i].x + fa.y * cwa[i].y + fa.z * cwa[i].z +
                fa.w * cwa[i].w + fc.x * cwb[i].x + fc.y * cwb[i].y +
                fc.z * cwb[i].z + fc.w * cwb[i].w;
    }
  }

  __shared__ float lds[4 * 8];
#pragma unroll
  for (int e = 0; e < E_DIM; ++e) {
    float v = acc[e];
    for (int off = 32; off; off >>= 1) v += __shfl_down(v, off, 64);
    if (lane == 0) lds[wave * 8 + e] = v;
  }
  __syncthreads();
  if (threadIdx.x < E_DIM) {
    out[(size_t)t * E_DIM + threadIdx.x] =
        lds[threadIdx.x] + lds[8 + threadIdx.x] + lds[16 + threadIdx.x] +
        lds[24 + threadIdx.x];
  }
}

// ---------------------------------------------------------------------------
// Kernel 4: gam_vector[i] = 0.99^(LEN_C-1-i)
// ---------------------------------------------------------------------------
__global__ void gam_kernel(float* __restrict__ out) {
  const int i = threadIdx.x;
  out[T_DIM * E_DIM + i] = powf(0.99f, (float)(LEN_C - 1 - i));
}

extern "C" void kernel_launch(void* const* d_in, const int* in_sizes, int n_in,
                              void* d_out, int out_size, void* d_ws,
                              size_t ws_size, hipStream_t stream) {
  const float* Fx = (const float*)d_in[0];         // [4,8,8,512]
  const float* Dis = (const float*)d_in[1];        // [8,512]
  const float* Fxe = (const float*)d_in[2];        // [2048,4,8,8,512]
  const float* W0 = (const float*)d_in[3];         // [4,8,512]
  float* out = (float*)d_out;                      // 16384 + 512

  float* err = (float*)d_ws;                       // 8 floats
  float* cw = (float*)((char*)d_ws + 64);          // 16384 floats, 16B aligned

  grad_kernel<<<1, 256, 0, stream>>>(Fx, Dis, W0, err);
  cw_kernel<<<W_ELEMS / 256, 256, 0, stream>>>(Fx, W0, err, cw);
  adapt_kernel<<<T_DIM, 256, 0, stream>>>(Fxe, cw, out);
  gam_kernel<<<1, LEN_C, 0, stream>>>(out);
}